// Round 1
// baseline (311.544 us; speedup 1.0000x reference)
//
#include <hip/hip_runtime.h>
#include <hip/hip_bf16.h>

using bf16 = __hip_bfloat16;

typedef __bf16 bf16x8 __attribute__((ext_vector_type(8)));
typedef __bf16 bf16x2v __attribute__((ext_vector_type(2)));
typedef float  f32x4  __attribute__((ext_vector_type(4)));
typedef float  f32x16 __attribute__((ext_vector_type(16)));

#define QK_SCALE 0.125f  // 64^-0.5

// ---- async global->LDS, 16B per lane (wave-uniform base + lane*16 on LDS side) ----
__device__ __forceinline__ void load_lds16(const bf16* g, bf16* l) {
  __builtin_amdgcn_global_load_lds(
      (const __attribute__((address_space(1))) unsigned int*)g,
      (__attribute__((address_space(3))) unsigned int*)l, 16, 0, 0);
}

// ---- pack two fp32 -> bf16x2 in one 32-bit reg (RNE per __bf16 cvt) ----
__device__ __forceinline__ unsigned pack_bf2(float a, float b) {
  bf16x2v v;
  v[0] = (__bf16)a;
  v[1] = (__bf16)b;
  return __builtin_bit_cast(unsigned, v);
}

// ---- fp32 -> bf16 bulk convert (RNE), float4-vectorized ----
struct alignas(8) bf16x4s { bf16 a, b, c, d; };
__global__ void f32_to_bf16_k(const float4* __restrict__ in, bf16x4s* __restrict__ out, int n4)
{
  const int i = blockIdx.x * blockDim.x + threadIdx.x;
  if (i < n4) {
    const float4 v = in[i];
    out[i] = { (bf16)v.x, (bf16)v.y, (bf16)v.z, (bf16)v.w };
  }
}

// =====================================================================================
// Generic NT GEMM: C[M,N] = alpha * A[M,K] @ B[N,K]^T (+bias), bf16 in, CT out, fp32 acc.
// (unchanged from previous round; used for QKV projection, QK^T, and output GEMM)
// =====================================================================================
template<int TM, int TN, int WM, int WN, bool BIAS, typename CT>
__global__ __launch_bounds__(256, 2)
void gemm_nt(const bf16* __restrict__ A, const bf16* __restrict__ B,
             CT* __restrict__ C, const float* __restrict__ bias,
             int K, int lda, int ldb, int ldc,
             long sA0, long sA1, long sB0, long sB1, long sC0, long sC1,
             int nz1, float alpha)
{
  constexpr int BK = 32;
  constexpr int LDE = TN + 8;
  constexpr unsigned SB_STAGE = (TM + TN) * BK * 2;
  constexpr unsigned SB_EP = (sizeof(CT) == 2) ? TM * LDE * 2 : 0;
  constexpr unsigned SBYTES = SB_STAGE > SB_EP ? SB_STAGE : SB_EP;
  __shared__ __align__(16) char smem[SBYTES];
  bf16* lsA = (bf16*)smem;
  bf16* lsB = lsA + TM * BK;

  const int z = blockIdx.z;
  A += (long)(z / nz1) * sA0 + (long)(z % nz1) * sA1;
  B += (long)(z / nz1) * sB0 + (long)(z % nz1) * sB1;
  C += (long)(z / nz1) * sC0 + (long)(z % nz1) * sC1;
  const int tm0 = blockIdx.y * TM;
  const int tn0 = blockIdx.x * TN;

  const int tid = threadIdx.x;
  const int w = tid >> 6, l = tid & 63;
  constexpr int WCOLS = TN / WN;
  const int wm = (w / WCOLS) * WM, wn = (w % WCOLS) * WN;
  constexpr int AM = WM / 16, AN = WN / 16;
  f32x4 acc[AM][AN] = {};
  const int kg = l >> 4, rl = l & 15;

  constexpr int RA = TM / 64, RB = TN / 64;
  const int srow0 = tid >> 2;
  const int scol = tid & 3;

  for (int k0 = 0; k0 < K; k0 += BK) {
#pragma unroll
    for (int r = 0; r < RA; ++r) {
      const int row = r * 64 + srow0;
      const int col8 = scol ^ ((row >> 1) & 3);
      load_lds16(A + (long)(tm0 + row) * lda + (k0 + col8 * 8),
                 &lsA[row * BK + scol * 8]);
    }
#pragma unroll
    for (int r = 0; r < RB; ++r) {
      const int row = r * 64 + srow0;
      const int col8 = scol ^ ((row >> 1) & 3);
      load_lds16(B + (long)(tn0 + row) * ldb + (k0 + col8 * 8),
                 &lsB[row * BK + scol * 8]);
    }
    __syncthreads();

    bf16x8 af[AM], bfr[AN];
#pragma unroll
    for (int i = 0; i < AM; ++i) {
      const int m = wm + i * 16 + rl;
      const int p = kg ^ ((m >> 1) & 3);
      af[i] = *(const bf16x8*)&lsA[m * BK + p * 8];
    }
#pragma unroll
    for (int j = 0; j < AN; ++j) {
      const int n = wn + j * 16 + rl;
      const int p = kg ^ ((n >> 1) & 3);
      bfr[j] = *(const bf16x8*)&lsB[n * BK + p * 8];
    }
#pragma unroll
    for (int i = 0; i < AM; ++i)
#pragma unroll
      for (int j = 0; j < AN; ++j)
        acc[i][j] = __builtin_amdgcn_mfma_f32_16x16x32_bf16(af[i], bfr[j], acc[i][j], 0, 0, 0);
    __syncthreads();
  }

  if constexpr (sizeof(CT) == 2) {
    bf16* ep = (bf16*)smem;
#pragma unroll
    for (int i = 0; i < AM; ++i) {
#pragma unroll
      for (int j = 0; j < AN; ++j) {
        const int col = wn + j * 16 + rl;
        float bv = 0.f;
        if (BIAS) bv = bias[tn0 + col];
#pragma unroll
        for (int v = 0; v < 4; ++v) {
          const int row = wm + i * 16 + (l >> 4) * 4 + v;
          ep[row * LDE + col] = (bf16)(acc[i][j][v] * alpha + bv);
        }
      }
    }
    __syncthreads();
    constexpr int CH = (TM * TN) / 2048;
#pragma unroll
    for (int c = 0; c < CH; ++c) {
      const int gidx = (c * 256 + tid) * 8;
      const int row = gidx / TN, col = gidx % TN;
      *(uint4*)&C[(long)(tm0 + row) * ldc + tn0 + col] = *(const uint4*)&ep[row * LDE + col];
    }
  } else {
#pragma unroll
    for (int i = 0; i < AM; ++i) {
#pragma unroll
      for (int j = 0; j < AN; ++j) {
        const int col = tn0 + wn + j * 16 + rl;
        float bv = 0.f;
        if (BIAS) bv = bias[col];
#pragma unroll
        for (int v = 0; v < 4; ++v) {
          const int row = tm0 + wm + i * 16 + (l >> 4) * 4 + v;
          C[(long)row * ldc + col] = (CT)(acc[i][j][v] * alpha + bv);
        }
      }
    }
  }
}

// =====================================================================================
// Batched transpose + convert: out[C x R](bf16) = (bf16)in[R x C]^T. 32x32 LDS tiles.
// =====================================================================================
template<typename TI>
__global__ void transpose_k(const TI* __restrict__ in, bf16* __restrict__ out,
                            int ldi, int ldo,
                            long sI0, long sI1, long sO0, long sO1, int nz1)
{
  __shared__ bf16 t[32][33];
  const int z = blockIdx.z;
  in  += (long)(z / nz1) * sI0 + (long)(z % nz1) * sI1;
  out += (long)(z / nz1) * sO0 + (long)(z % nz1) * sO1;
  const int c0 = blockIdx.x * 32, r0 = blockIdx.y * 32;
  const int x = threadIdx.x, y = threadIdx.y;
#pragma unroll
  for (int dy = 0; dy < 32; dy += 8)
    t[y + dy][x] = (bf16)(float)in[(long)(r0 + y + dy) * ldi + c0 + x];
  __syncthreads();
#pragma unroll
  for (int dy = 0; dy < 32; dy += 8)
    out[(long)(c0 + y + dy) * ldo + r0 + x] = t[x][y + dy];
}

// =====================================================================================
// FUSED talking-heads middle + PV  (replaces mix_softmax_mix + the 64x64 PV GEMM).
// One block per (b, 16-row i-tile): grid 256 = 1 block/CU, 512 threads (8 waves).
// Pass 1 (16 j-tiles of 64): stage S h-pair-packed -> premix via ONE 32x32x16 MFMA
//   (A rows 0-15 = hi coeffs, 16-31 = lo residuals; hi+lo land in same lane as regs
//   k and k+8) -> exp(x-10) -> Z[g,i] accumulated in registers (each wave owns 2 i).
// Pass 2: recompute p-hat, *1/Z, pack bf16 pairs, cross-half exchange via 2 shfl_xor,
//   postmix 32x32x16 MFMA -> P tile to LDS -> PV via 16x16x32 MFMA (V^T frags straight
//   from L2; b = blockIdx.x&3 pins each batch's VT to one XCD's L2) -> Obuf direct.
// Eliminates 128MB P write + 128MB P re-read; 2nd S read is L3-resident.
// =====================================================================================
#define LOADS(t)                                                               \
  _Pragma("unroll")                                                            \
  for (int it = 0; it < 4; ++it) {                                             \
    const int u = it * 512 + tid;                                              \
    const long off = (long)(u >> 8) * 2097152 + (long)((u >> 4) & 15) * 1024   \
                   + (long)(t) * 64 + (u & 15) * 4;                            \
    rA[it] = *(const uint2*)(Sb + off);                                        \
    rB[it] = *(const uint2*)(Sb + off + 1048576);                              \
  }

#define STAGE()                                                                \
  _Pragma("unroll")                                                            \
  for (int it = 0; it < 4; ++it) {                                             \
    const int u = it * 512 + tid;                                              \
    uint4 wv;                                                                  \
    wv.x = (rA[it].x & 0xFFFFu) | (rB[it].x << 16);                            \
    wv.y = (rA[it].x >> 16)     | (rB[it].x & 0xFFFF0000u);                    \
    wv.z = (rA[it].y & 0xFFFFu) | (rB[it].y << 16);                            \
    wv.w = (rA[it].y >> 16)     | (rB[it].y & 0xFFFF0000u);                    \
    *(uint4*)&SbL[(u >> 8) * 1088 + ((u >> 4) & 15) * 68 + (u & 15) * 4] = wv; \
  }

__global__ __launch_bounds__(512, 1)
void mix_pv_fused(const bf16* __restrict__ S, const bf16* __restrict__ VTm,
                  bf16* __restrict__ O,
                  const float* __restrict__ mixpre, const float* __restrict__ mixpost)
{
  // SbL: S tile packed as h-pairs, [h2(8)][i(16)][j(68 pad)] u32 words = 34.8 KB
  // Pl : P tile [G(16)][i(16)][j(72 pad)] bf16 = 36.9 KB  (strides tuned: all <=2-way)
  __shared__ __align__(16) unsigned int SbL[8 * 16 * 68];
  __shared__ __align__(16) __bf16 Pl[16 * 16 * 72];
  __shared__ float preS[256], postS[256];

  const int tid = threadIdx.x;
  const int l = tid & 63, w = tid >> 6;      // 8 waves
  const int bx = blockIdx.x;
  const int b = bx & 3;                       // batch -> XCD-pinned (bx%8 fixes b)
  const int i0 = (bx >> 2) << 4;

  if (tid < 256) preS[tid] = mixpre[tid];
  else           postS[tid - 256] = mixpost[tid - 256];
  __syncthreads();

  const int col = l & 31;          // D col / B row (32x32 ops)
  const int H = l >> 5;            // k-half: k = H*8 + e
  const int g16 = l & 15;
  const bool loRow = (l & 16) != 0;

  // A-frags: rows 0-15 hi bf16 coeffs, rows 16-31 lo residuals (hi/lo in one MFMA)
  bf16x8 aPre, aPost;
#pragma unroll
  for (int e = 0; e < 8; ++e) {
    const int k = H * 8 + e;
    {
      const float c = preS[k * 16 + g16];
      const __bf16 hi = (__bf16)c;
      aPre[e] = loRow ? (__bf16)(c - (float)hi) : hi;
    }
    {
      const float c = postS[k * 16 + g16];
      const __bf16 hi = (__bf16)c;
      aPost[e] = loRow ? (__bf16)(c - (float)hi) : hi;
    }
  }

  const bf16* Sb = S + (long)b * 16777216 + (long)i0 * 1024;

  uint2 rA[4], rB[4];
  float zac[2][8];
#pragma unroll
  for (int il = 0; il < 2; ++il)
#pragma unroll
    for (int k = 0; k < 8; ++k) zac[il][k] = 0.f;

  // ---------------- pass 1: Z only ----------------
  LOADS(0)
  for (int t = 0; t < 16; ++t) {
    STAGE()
    __syncthreads();
    if (t < 15) { LOADS(t + 1) }   // prefetch: latency hides under mix
#pragma unroll
    for (int il = 0; il < 2; ++il) {
      const int ic = 2 * w + il;   // wave-exclusive i rows
#pragma unroll
      for (int jh = 0; jh < 2; ++jh) {
        const int base = H * 4352 + ic * 68 + jh * 32 + col;
        uint4 bw;
        bw.x = SbL[base];
        bw.y = SbL[base + 1088];
        bw.z = SbL[base + 2176];
        bw.w = SbL[base + 3264];
        const bf16x8 bfr = __builtin_bit_cast(bf16x8, bw);
        f32x16 d = {};
        d = __builtin_amdgcn_mfma_f32_32x32x16_bf16(aPre, bfr, d, 0, 0, 0);
#pragma unroll
        for (int k = 0; k < 8; ++k)
          zac[il][k] += __expf(d[k] + d[k + 8] - 10.f);  // rows g and g+16 pair
      }
    }
    __syncthreads();
  }

  // Z reduce over the 32 j-columns of each half (same-g lanes), then reciprocal
#pragma unroll
  for (int il = 0; il < 2; ++il)
#pragma unroll
    for (int k = 0; k < 8; ++k) {
      float z = zac[il][k];
      z += __shfl_xor(z, 1, 64);
      z += __shfl_xor(z, 2, 64);
      z += __shfl_xor(z, 4, 64);
      z += __shfl_xor(z, 8, 64);
      z += __shfl_xor(z, 16, 64);
      zac[il][k] = 1.f / z;        // reuse as rZ
    }

  // ---------------- pass 2: normalize + postmix + PV ----------------
  f32x4 acc[2][4] = {};
  LOADS(0)
  for (int t = 0; t < 16; ++t) {
    STAGE()
    __syncthreads();
    if (t < 15) { LOADS(t + 1) }
#pragma unroll
    for (int il = 0; il < 2; ++il) {
      const int ic = 2 * w + il;
#pragma unroll
      for (int jh = 0; jh < 2; ++jh) {
        const int base = H * 4352 + ic * 68 + jh * 32 + col;
        uint4 bw;
        bw.x = SbL[base];
        bw.y = SbL[base + 1088];
        bw.z = SbL[base + 2176];
        bw.w = SbL[base + 3264];
        const bf16x8 bfr = __builtin_bit_cast(bf16x8, bw);
        f32x16 d = {};
        d = __builtin_amdgcn_mfma_f32_32x32x16_bf16(aPre, bfr, d, 0, 0, 0);
        float pn[8];
#pragma unroll
        for (int k = 0; k < 8; ++k)
          pn[k] = __expf(d[k] + d[k + 8] - 10.f) * zac[il][k];
        // pack g-pairs; exchange the 2 words the other half needs (g 4-7 <-> 8-11)
        const unsigned pA = pack_bf2(pn[0], pn[1]);
        const unsigned pB = pack_bf2(pn[2], pn[3]);
        const unsigned pC = pack_bf2(pn[4], pn[5]);
        const unsigned pD = pack_bf2(pn[6], pn[7]);
        const unsigned x0 = (unsigned)__shfl_xor((int)(H ? pA : pC), 32, 64);
        const unsigned x1 = (unsigned)__shfl_xor((int)(H ? pB : pD), 32, 64);
        uint4 praw;
        praw.x = H ? x0 : pA;
        praw.y = H ? x1 : pB;
        praw.z = H ? pC : x0;
        praw.w = H ? pD : x1;
        const bf16x8 pfr = __builtin_bit_cast(bf16x8, praw);
        f32x16 d2 = {};
        d2 = __builtin_amdgcn_mfma_f32_32x32x16_bf16(aPost, pfr, d2, 0, 0, 0);
#pragma unroll
        for (int k = 0; k < 8; ++k) {
          const int G = k + (k & 4) + (H << 2);   // lane's G-set
          Pl[G * 1152 + ic * 72 + jh * 32 + col] = (__bf16)(d2[k] + d2[k + 8]);
        }
      }
    }
    __syncthreads();
    // PV on this j-tile: each wave owns G = {w, w+8}
    const int jt = t * 64;
#pragma unroll
    for (int gi = 0; gi < 2; ++gi) {
      const int G = w + gi * 8;
      const bf16* vtg = VTm + ((long)(b * 16 + G) * 64) * 1024;
#pragma unroll
      for (int kc = 0; kc < 2; ++kc) {
        const bf16x8 af = *(const bf16x8*)&Pl[G * 1152 + (l & 15) * 72 + kc * 32 + (l >> 4) * 8];
#pragma unroll
        for (int dt = 0; dt < 4; ++dt) {
          const bf16x8 bfv = *(const bf16x8*)&vtg[(long)(dt * 16 + (l & 15)) * 1024
                                                 + jt + kc * 32 + (l >> 4) * 8];
          acc[gi][dt] = __builtin_amdgcn_mfma_f32_16x16x32_bf16(af, bfv, acc[gi][dt], 0, 0, 0);
        }
      }
    }
  }

  // epilogue: direct bf16 stores (32B segments per quad; L2 merges)
  const long ob = (long)(b * 1024 + i0) * 1024;
#pragma unroll
  for (int gi = 0; gi < 2; ++gi) {
    const int G = w + gi * 8;
#pragma unroll
    for (int dt = 0; dt < 4; ++dt)
#pragma unroll
      for (int v = 0; v < 4; ++v)
        O[ob + (long)((l >> 4) * 4 + v) * 1024 + G * 64 + dt * 16 + (l & 15)] =
            (bf16)acc[gi][dt][v];
  }
}

// =====================================================================================
extern "C" void kernel_launch(void* const* d_in, const int* in_sizes, int n_in,
                              void* d_out, int out_size, void* d_ws, size_t ws_size,
                              hipStream_t stream)
{
  const float* x     = (const float*)d_in[0];
  const float* Wq    = (const float*)d_in[1];
  const float* Wkv   = (const float*)d_in[2];
  const float* mpre  = (const float*)d_in[3];
  const float* mpost = (const float*)d_in[4];
  const float* Wo    = (const float*)d_in[5];
  const float* bo    = (const float*)d_in[6];
  float* out = (float*)d_out;

  char* ws = (char*)d_ws;
  const size_t MB = 1024 * 1024;
  if (ws_size < 184 * MB) return;
  bf16* xb   = (bf16*)(ws);             // [4096,1024]           8 MB
  bf16* QKV  = (bf16*)(ws + 8 * MB);    // [4096,3072] Q|K|V    24 MB
  bf16* WT   = (bf16*)(ws + 32 * MB);   // [3072,1024] WqT|WkvT  6 MB
  bf16* WoT  = (bf16*)(ws + 38 * MB);   // [1024,1024]           2 MB
  bf16* VT   = (bf16*)(ws + 40 * MB);   // [4,16,64,1024]        8 MB
  bf16* Obuf = (bf16*)(ws + 48 * MB);   // [4096,1024]           8 MB
  bf16* Sbuf = (bf16*)(ws + 56 * MB);   // [4,16,1024,1024]    128 MB

  const dim3 tb(32, 8, 1);

  // 0) convert x to bf16
  f32_to_bf16_k<<<4096, 256, 0, stream>>>((const float4*)x, (bf16x4s*)xb, 1048576);

  // 1) weight transposes + fp32->bf16
  transpose_k<float><<<dim3(32, 32, 1), tb, 0, stream>>>(Wq,  WT,           1024, 1024, 0, 0, 0, 0, 1);
  transpose_k<float><<<dim3(64, 32, 1), tb, 0, stream>>>(Wkv, WT + 1048576, 2048, 1024, 0, 0, 0, 0, 1);
  transpose_k<float><<<dim3(32, 32, 1), tb, 0, stream>>>(Wo,  WoT,          1024, 1024, 0, 0, 0, 0, 1);

  // 2) fused projection: QKV = x @ [Wq | Wkv]
  gemm_nt<128, 128, 64, 64, false, bf16><<<dim3(24, 32, 1), 256, 0, stream>>>(
      xb, WT, QKV, nullptr, 1024, 1024, 1024, 3072, 0, 0, 0, 0, 0, 0, 1, 1.f);

  // 3) V^T per (b,G): [1024,64] -> [64,1024]
  transpose_k<bf16><<<dim3(2, 32, 64), tb, 0, stream>>>(
      QKV + 2048, VT, 3072, 1024,
      3145728, 64, 16L * 65536, 65536, 16);

  // 4) S = SCALE * Q_bh @ K_bh^T  (z = b*16+h)
  gemm_nt<128, 128, 64, 64, false, bf16><<<dim3(8, 8, 64), 256, 0, stream>>>(
      QKV, QKV + 1024, Sbuf, nullptr, 64, 3072, 3072, 1024,
      3145728, 64, 3145728, 64, 16L * 1048576, 1048576, 16, QK_SCALE);

  // 5+6) FUSED premix + softmax + postmix + PV  -> Obuf   (one block per CU)
  mix_pv_fused<<<dim3(256, 1, 1), 512, 0, stream>>>(Sbuf, VT, Obuf, mpre, mpost);

  // 7) out = O @ Wo + bo  (fp32 output + fp32 bias)
  gemm_nt<128, 128, 64, 64, true, float><<<dim3(8, 32, 1), 256, 0, stream>>>(
      Obuf, WoT, out, bo, 1024, 1024, 1024, 1024, 0, 0, 0, 0, 0, 0, 1, 1.f);
}

// Round 2
// 291.653 us; speedup vs baseline: 1.0682x; 1.0682x over previous
//
#include <hip/hip_runtime.h>
#include <hip/hip_bf16.h>

using bf16 = __hip_bfloat16;

typedef __bf16 bf16x8 __attribute__((ext_vector_type(8)));
typedef __bf16 bf16x2v __attribute__((ext_vector_type(2)));
typedef float  f32x4  __attribute__((ext_vector_type(4)));
typedef float  f32x16 __attribute__((ext_vector_type(16)));

#define QK_SCALE 0.125f  // 64^-0.5

// ---- async global->LDS, 16B per lane (wave-uniform base + lane*16 on LDS side) ----
__device__ __forceinline__ void load_lds16(const bf16* g, bf16* l) {
  __builtin_amdgcn_global_load_lds(
      (const __attribute__((address_space(1))) unsigned int*)g,
      (__attribute__((address_space(3))) unsigned int*)l, 16, 0, 0);
}

// ---- pack two fp32 -> bf16x2 in one 32-bit reg (RNE per __bf16 cvt) ----
__device__ __forceinline__ unsigned pack_bf2(float a, float b) {
  bf16x2v v;
  v[0] = (__bf16)a;
  v[1] = (__bf16)b;
  return __builtin_bit_cast(unsigned, v);
}

// ---- fp32 -> bf16 bulk convert (RNE), float4-vectorized ----
struct alignas(8) bf16x4s { bf16 a, b, c, d; };
__global__ void f32_to_bf16_k(const float4* __restrict__ in, bf16x4s* __restrict__ out, int n4)
{
  const int i = blockIdx.x * blockDim.x + threadIdx.x;
  if (i < n4) {
    const float4 v = in[i];
    out[i] = { (bf16)v.x, (bf16)v.y, (bf16)v.z, (bf16)v.w };
  }
}

// =====================================================================================
// Generic NT GEMM: C[M,N] = alpha * A[M,K] @ B[N,K]^T (+bias), bf16 in, CT out, fp32 acc.
// =====================================================================================
template<int TM, int TN, int WM, int WN, bool BIAS, typename CT>
__global__ __launch_bounds__(256, 2)
void gemm_nt(const bf16* __restrict__ A, const bf16* __restrict__ B,
             CT* __restrict__ C, const float* __restrict__ bias,
             int K, int lda, int ldb, int ldc,
             long sA0, long sA1, long sB0, long sB1, long sC0, long sC1,
             int nz1, float alpha)
{
  constexpr int BK = 32;
  constexpr int LDE = TN + 8;
  constexpr unsigned SB_STAGE = (TM + TN) * BK * 2;
  constexpr unsigned SB_EP = (sizeof(CT) == 2) ? TM * LDE * 2 : 0;
  constexpr unsigned SBYTES = SB_STAGE > SB_EP ? SB_STAGE : SB_EP;
  __shared__ __align__(16) char smem[SBYTES];
  bf16* lsA = (bf16*)smem;
  bf16* lsB = lsA + TM * BK;

  const int z = blockIdx.z;
  A += (long)(z / nz1) * sA0 + (long)(z % nz1) * sA1;
  B += (long)(z / nz1) * sB0 + (long)(z % nz1) * sB1;
  C += (long)(z / nz1) * sC0 + (long)(z % nz1) * sC1;
  const int tm0 = blockIdx.y * TM;
  const int tn0 = blockIdx.x * TN;

  const int tid = threadIdx.x;
  const int w = tid >> 6, l = tid & 63;
  constexpr int WCOLS = TN / WN;
  const int wm = (w / WCOLS) * WM, wn = (w % WCOLS) * WN;
  constexpr int AM = WM / 16, AN = WN / 16;
  f32x4 acc[AM][AN] = {};
  const int kg = l >> 4, rl = l & 15;

  constexpr int RA = TM / 64, RB = TN / 64;
  const int srow0 = tid >> 2;
  const int scol = tid & 3;

  for (int k0 = 0; k0 < K; k0 += BK) {
#pragma unroll
    for (int r = 0; r < RA; ++r) {
      const int row = r * 64 + srow0;
      const int col8 = scol ^ ((row >> 1) & 3);
      load_lds16(A + (long)(tm0 + row) * lda + (k0 + col8 * 8),
                 &lsA[row * BK + scol * 8]);
    }
#pragma unroll
    for (int r = 0; r < RB; ++r) {
      const int row = r * 64 + srow0;
      const int col8 = scol ^ ((row >> 1) & 3);
      load_lds16(B + (long)(tn0 + row) * ldb + (k0 + col8 * 8),
                 &lsB[row * BK + scol * 8]);
    }
    __syncthreads();

    bf16x8 af[AM], bfr[AN];
#pragma unroll
    for (int i = 0; i < AM; ++i) {
      const int m = wm + i * 16 + rl;
      const int p = kg ^ ((m >> 1) & 3);
      af[i] = *(const bf16x8*)&lsA[m * BK + p * 8];
    }
#pragma unroll
    for (int j = 0; j < AN; ++j) {
      const int n = wn + j * 16 + rl;
      const int p = kg ^ ((n >> 1) & 3);
      bfr[j] = *(const bf16x8*)&lsB[n * BK + p * 8];
    }
#pragma unroll
    for (int i = 0; i < AM; ++i)
#pragma unroll
      for (int j = 0; j < AN; ++j)
        acc[i][j] = __builtin_amdgcn_mfma_f32_16x16x32_bf16(af[i], bfr[j], acc[i][j], 0, 0, 0);
    __syncthreads();
  }

  if constexpr (sizeof(CT) == 2) {
    bf16* ep = (bf16*)smem;
#pragma unroll
    for (int i = 0; i < AM; ++i) {
#pragma unroll
      for (int j = 0; j < AN; ++j) {
        const int col = wn + j * 16 + rl;
        float bv = 0.f;
        if (BIAS) bv = bias[tn0 + col];
#pragma unroll
        for (int v = 0; v < 4; ++v) {
          const int row = wm + i * 16 + (l >> 4) * 4 + v;
          ep[row * LDE + col] = (bf16)(acc[i][j][v] * alpha + bv);
        }
      }
    }
    __syncthreads();
    constexpr int CH = (TM * TN) / 2048;
#pragma unroll
    for (int c = 0; c < CH; ++c) {
      const int gidx = (c * 256 + tid) * 8;
      const int row = gidx / TN, col = gidx % TN;
      *(uint4*)&C[(long)(tm0 + row) * ldc + tn0 + col] = *(const uint4*)&ep[row * LDE + col];
    }
  } else {
#pragma unroll
    for (int i = 0; i < AM; ++i) {
#pragma unroll
      for (int j = 0; j < AN; ++j) {
        const int col = tn0 + wn + j * 16 + rl;
        float bv = 0.f;
        if (BIAS) bv = bias[col];
#pragma unroll
        for (int v = 0; v < 4; ++v) {
          const int row = tm0 + wm + i * 16 + (l >> 4) * 4 + v;
          C[(long)row * ldc + col] = (CT)(acc[i][j][v] * alpha + bv);
        }
      }
    }
  }
}

// =====================================================================================
// Batched transpose + convert: out[C x R](bf16) = (bf16)in[R x C]^T. 32x32 LDS tiles.
// =====================================================================================
template<typename TI>
__global__ void transpose_k(const TI* __restrict__ in, bf16* __restrict__ out,
                            int ldi, int ldo,
                            long sI0, long sI1, long sO0, long sO1, int nz1)
{
  __shared__ bf16 t[32][33];
  const int z = blockIdx.z;
  in  += (long)(z / nz1) * sI0 + (long)(z % nz1) * sI1;
  out += (long)(z / nz1) * sO0 + (long)(z % nz1) * sO1;
  const int c0 = blockIdx.x * 32, r0 = blockIdx.y * 32;
  const int x = threadIdx.x, y = threadIdx.y;
#pragma unroll
  for (int dy = 0; dy < 32; dy += 8)
    t[y + dy][x] = (bf16)(float)in[(long)(r0 + y + dy) * ldi + c0 + x];
  __syncthreads();
#pragma unroll
  for (int dy = 0; dy < 32; dy += 8)
    out[(long)(c0 + y + dy) * ldo + r0 + x] = t[x][y + dy];
}

// =====================================================================================
// FUSED talking-heads middle + PV, v3: deep-pipelined single-barrier schedule.
// Grid 256 (4b x 64 i-tiles of 16), 512 threads (8 waves), 1 block/CU.
//  - S staged DIRECT via global_load_lds (32 x 1KB per 64-j tile), linear [h][i][j]
//    LDS layout, per-h stride 1032 elems (2064 B): premix gather = 8 ds_read_u16,
//    2-way bank aliasing (free).
//  - Double-buffered S stage AND P tile -> ONE barrier per tile-iteration.
//    Pipeline per iter t: barrier | stage(t+1) | PV(t-1) | loadV(t)->regs | mix(t)->Pl.
//    Every load issued at t drains at barrier t+1 (a full compute phase of cover).
//  - V frags prefetched one tile ahead into 16 uint4 regs; PV never waits on L2.
// Math identical to verified v2: 32x32x16 premix/postmix MFMA with hi/lo coeff rows,
// no-max softmax exp(x-10), register Z, cross-half shuffle for postmix B-frags.
// =====================================================================================
__global__ __launch_bounds__(512, 1)
void mix_pv_fused(const bf16* __restrict__ S, const bf16* __restrict__ VTm,
                  bf16* __restrict__ O,
                  const float* __restrict__ mixpre, const float* __restrict__ mixpost)
{
  constexpr int SH = 1032;                         // per-h stride (16*64 + 8 pad)
  __shared__ __align__(16) __bf16 Sst[2][16 * SH]; // 2 x 33024 B
  __shared__ __align__(16) __bf16 Pl[2][16 * 16 * 72]; // 2 x 36864 B
  __shared__ float preS[256], postS[256];

  const int tid = threadIdx.x;
  const int l = tid & 63, w = tid >> 6;            // 8 waves
  const int bx = blockIdx.x;
  const int b = bx & 3;                            // batch -> XCD-pinned
  const int i0 = (bx >> 2) << 4;

  if (tid < 256) preS[tid] = mixpre[tid];
  else           postS[tid - 256] = mixpost[tid - 256];
  __syncthreads();

  const int col = l & 31;          // D col / B row (32x32 ops)
  const int H = l >> 5;            // k-half: k = H*8 + e
  const int g16 = l & 15;
  const bool loRow = (l & 16) != 0;
  const int rl16 = l & 15, kg4 = l >> 4;

  // A-frags: rows 0-15 hi bf16 coeffs, rows 16-31 lo residuals (hi/lo in one MFMA)
  bf16x8 aPre, aPost;
#pragma unroll
  for (int e = 0; e < 8; ++e) {
    const int k = H * 8 + e;
    {
      const float c = preS[k * 16 + g16];
      const __bf16 hi = (__bf16)c;
      aPre[e] = loRow ? (__bf16)(c - (float)hi) : hi;
    }
    {
      const float c = postS[k * 16 + g16];
      const __bf16 hi = (__bf16)c;
      aPost[e] = loRow ? (__bf16)(c - (float)hi) : hi;
    }
  }

  const bf16* Sb = S + (long)b * 16777216 + (long)i0 * 1024;

  // ---- async stage of tile t (64 j-cols) into Sst[bufi]: 4 x 1KB gl_lds per wave ----
  auto stage = [&](int t, int bufi) {
    const int jt = t * 64;
#pragma unroll
    for (int s = 0; s < 4; ++s) {
      const int h = 2 * w + (s >> 1);
      const int half = s & 1;
      const int i = half * 8 + (l >> 3);
      const int j = (l & 7) * 8;
      load_lds16(Sb + (long)h * 1048576 + (long)i * 1024 + jt + j,
                 (bf16*)&Sst[bufi][h * SH + half * 512 + l * 8]);
    }
  };

  float zac[2][8];
#pragma unroll
  for (int il = 0; il < 2; ++il)
#pragma unroll
    for (int k = 0; k < 8; ++k) zac[il][k] = 0.f;

  // ================= pass 1: Z only (premix + exp), 1 barrier/iter =================
  stage(0, 0);
  for (int t = 0; t < 16; ++t) {
    __syncthreads();                     // stage(t) drained here
    if (t < 15) stage(t + 1, (t + 1) & 1);
    const __bf16* sb = Sst[t & 1];
#pragma unroll
    for (int il = 0; il < 2; ++il) {
      const int ic = 2 * w + il;         // wave-exclusive i rows
#pragma unroll
      for (int jh = 0; jh < 2; ++jh) {
        bf16x8 bfr;
#pragma unroll
        for (int e = 0; e < 8; ++e)
          bfr[e] = sb[(H * 8 + e) * SH + ic * 64 + jh * 32 + col];
        f32x16 d = {};
        d = __builtin_amdgcn_mfma_f32_32x32x16_bf16(aPre, bfr, d, 0, 0, 0);
#pragma unroll
        for (int k = 0; k < 8; ++k)
          zac[il][k] += __expf(d[k] + d[k + 8] - 10.f);  // rows g and g+16 pair
      }
    }
  }

  // Z reduce over the 32 j-columns of each half (same-g lanes), then reciprocal
#pragma unroll
  for (int il = 0; il < 2; ++il)
#pragma unroll
    for (int k = 0; k < 8; ++k) {
      float z = zac[il][k];
      z += __shfl_xor(z, 1, 64);
      z += __shfl_xor(z, 2, 64);
      z += __shfl_xor(z, 4, 64);
      z += __shfl_xor(z, 8, 64);
      z += __shfl_xor(z, 16, 64);
      zac[il][k] = 1.f / z;              // reuse as rZ
    }

  // ================= pass 2: mix + PV, software-pipelined, 1 barrier/iter =========
  f32x4 acc[2][4] = {};
  uint4 vreg[16];                        // V frags for tile t (2G x 2kc x 4dt)
  const bf16* vtg0 = VTm + ((long)(b * 16 + w) * 64) * 1024;
  const bf16* vtg1 = VTm + ((long)(b * 16 + w + 8) * 64) * 1024;

  stage(0, 0);
  for (int t = 0; t <= 16; ++t) {
    __syncthreads();   // drains stage(t) + loadV(t-1); Pl[(t-1)&1] complete (lgkm)

    if (t < 15) stage(t + 1, (t + 1) & 1);

    if (t > 0) {
      // ---- PV(t-1): Pl[(t-1)&1] x vreg (V of tile t-1, prefetched last iter) ----
      const __bf16* pb = Pl[(t - 1) & 1];
#pragma unroll
      for (int gi = 0; gi < 2; ++gi) {
        const int G = w + gi * 8;
#pragma unroll
        for (int kc = 0; kc < 2; ++kc) {
          const bf16x8 af = *(const bf16x8*)&pb[G * 1152 + rl16 * 72 + kc * 32 + kg4 * 8];
#pragma unroll
          for (int dt = 0; dt < 4; ++dt) {
            const bf16x8 bfv = __builtin_bit_cast(bf16x8, vreg[gi * 8 + kc * 4 + dt]);
            acc[gi][dt] = __builtin_amdgcn_mfma_f32_16x16x32_bf16(af, bfv, acc[gi][dt], 0, 0, 0);
          }
        }
      }
    }

    if (t < 16) {
      // ---- prefetch V frags for tile t (consumed by PV at iter t+1) ----
      const int jt = t * 64;
#pragma unroll
      for (int kc = 0; kc < 2; ++kc)
#pragma unroll
        for (int dt = 0; dt < 4; ++dt) {
          vreg[kc * 4 + dt] =
              *(const uint4*)&vtg0[(long)(dt * 16 + rl16) * 1024 + jt + kc * 32 + kg4 * 8];
          vreg[8 + kc * 4 + dt] =
              *(const uint4*)&vtg1[(long)(dt * 16 + rl16) * 1024 + jt + kc * 32 + kg4 * 8];
        }

      // ---- premix + exp + normalize + postmix -> Pl[t&1] ----
      const __bf16* sb = Sst[t & 1];
      __bf16* pl = Pl[t & 1];
#pragma unroll
      for (int il = 0; il < 2; ++il) {
        const int ic = 2 * w + il;
#pragma unroll
        for (int jh = 0; jh < 2; ++jh) {
          bf16x8 bfr;
#pragma unroll
          for (int e = 0; e < 8; ++e)
            bfr[e] = sb[(H * 8 + e) * SH + ic * 64 + jh * 32 + col];
          f32x16 d = {};
          d = __builtin_amdgcn_mfma_f32_32x32x16_bf16(aPre, bfr, d, 0, 0, 0);
          float pn[8];
#pragma unroll
          for (int k = 0; k < 8; ++k)
            pn[k] = __expf(d[k] + d[k + 8] - 10.f) * zac[il][k];
          // pack g-pairs; exchange the 2 words the other half needs
          const unsigned pA = pack_bf2(pn[0], pn[1]);
          const unsigned pB = pack_bf2(pn[2], pn[3]);
          const unsigned pC = pack_bf2(pn[4], pn[5]);
          const unsigned pD = pack_bf2(pn[6], pn[7]);
          const unsigned x0 = (unsigned)__shfl_xor((int)(H ? pA : pC), 32, 64);
          const unsigned x1 = (unsigned)__shfl_xor((int)(H ? pB : pD), 32, 64);
          uint4 praw;
          praw.x = H ? x0 : pA;
          praw.y = H ? x1 : pB;
          praw.z = H ? pC : x0;
          praw.w = H ? pD : x1;
          const bf16x8 pfr = __builtin_bit_cast(bf16x8, praw);
          f32x16 d2 = {};
          d2 = __builtin_amdgcn_mfma_f32_32x32x16_bf16(aPost, pfr, d2, 0, 0, 0);
#pragma unroll
          for (int k = 0; k < 8; ++k) {
            const int G = k + (k & 4) + (H << 2);   // lane's G-set
            pl[G * 1152 + ic * 72 + jh * 32 + col] = (__bf16)(d2[k] + d2[k + 8]);
          }
        }
      }
    }
  }

  // epilogue: direct bf16 stores (32B segments per quad; L2 merges)
  const long ob = (long)(b * 1024 + i0) * 1024;
#pragma unroll
  for (int gi = 0; gi < 2; ++gi) {
    const int G = w + gi * 8;
#pragma unroll
    for (int dt = 0; dt < 4; ++dt)
#pragma unroll
      for (int v = 0; v < 4; ++v)
        O[ob + (long)((l >> 4) * 4 + v) * 1024 + G * 64 + dt * 16 + rl16] =
            (bf16)acc[gi][dt][v];
  }
}

// =====================================================================================
extern "C" void kernel_launch(void* const* d_in, const int* in_sizes, int n_in,
                              void* d_out, int out_size, void* d_ws, size_t ws_size,
                              hipStream_t stream)
{
  const float* x     = (const float*)d_in[0];
  const float* Wq    = (const float*)d_in[1];
  const float* Wkv   = (const float*)d_in[2];
  const float* mpre  = (const float*)d_in[3];
  const float* mpost = (const float*)d_in[4];
  const float* Wo    = (const float*)d_in[5];
  const float* bo    = (const float*)d_in[6];
  float* out = (float*)d_out;

  char* ws = (char*)d_ws;
  const size_t MB = 1024 * 1024;
  if (ws_size < 184 * MB) return;
  bf16* xb   = (bf16*)(ws);             // [4096,1024]           8 MB
  bf16* QKV  = (bf16*)(ws + 8 * MB);    // [4096,3072] Q|K|V    24 MB
  bf16* WT   = (bf16*)(ws + 32 * MB);   // [3072,1024] WqT|WkvT  6 MB
  bf16* WoT  = (bf16*)(ws + 38 * MB);   // [1024,1024]           2 MB
  bf16* VT   = (bf16*)(ws + 40 * MB);   // [4,16,64,1024]        8 MB
  bf16* Obuf = (bf16*)(ws + 48 * MB);   // [4096,1024]           8 MB
  bf16* Sbuf = (bf16*)(ws + 56 * MB);   // [4,16,1024,1024]    128 MB

  const dim3 tb(32, 8, 1);

  // 0) convert x to bf16
  f32_to_bf16_k<<<4096, 256, 0, stream>>>((const float4*)x, (bf16x4s*)xb, 1048576);

  // 1) weight transposes + fp32->bf16
  transpose_k<float><<<dim3(32, 32, 1), tb, 0, stream>>>(Wq,  WT,           1024, 1024, 0, 0, 0, 0, 1);
  transpose_k<float><<<dim3(64, 32, 1), tb, 0, stream>>>(Wkv, WT + 1048576, 2048, 1024, 0, 0, 0, 0, 1);
  transpose_k<float><<<dim3(32, 32, 1), tb, 0, stream>>>(Wo,  WoT,          1024, 1024, 0, 0, 0, 0, 1);

  // 2) fused projection: QKV = x @ [Wq | Wkv]
  gemm_nt<128, 128, 64, 64, false, bf16><<<dim3(24, 32, 1), 256, 0, stream>>>(
      xb, WT, QKV, nullptr, 1024, 1024, 1024, 3072, 0, 0, 0, 0, 0, 0, 1, 1.f);

  // 3) V^T per (b,G): [1024,64] -> [64,1024]
  transpose_k<bf16><<<dim3(2, 32, 64), tb, 0, stream>>>(
      QKV + 2048, VT, 3072, 1024,
      3145728, 64, 16L * 65536, 65536, 16);

  // 4) S = SCALE * Q_bh @ K_bh^T  (z = b*16+h)
  gemm_nt<128, 128, 64, 64, false, bf16><<<dim3(8, 8, 64), 256, 0, stream>>>(
      QKV, QKV + 1024, Sbuf, nullptr, 64, 3072, 3072, 1024,
      3145728, 64, 3145728, 64, 16L * 1048576, 1048576, 16, QK_SCALE);

  // 5+6) FUSED premix + softmax + postmix + PV  -> Obuf (pipelined v3)
  mix_pv_fused<<<dim3(256, 1, 1), 512, 0, stream>>>(Sbuf, VT, Obuf, mpre, mpost);

  // 7) out = O @ Wo + bo  (fp32 output + fp32 bias)
  gemm_nt<128, 128, 64, 64, true, float><<<dim3(8, 32, 1), 256, 0, stream>>>(
      Obuf, WoT, out, bo, 1024, 1024, 1024, 1024, 0, 0, 0, 0, 0, 0, 1, 1.f);
}